// Round 9
// baseline (374.721 us; speedup 1.0000x reference)
//
#include <hip/hip_runtime.h>
#include <math.h>

#define NPn 30000
#define EPn 480000
#define NLl 48
#define ELl 144
#define Tn 96
#define NAn 11
#define Dn 256
#define N1 49
#define NEGf (-1000000000.0f)
#define NSTATES 97
#define CHN 125
#define PC 13            // P columns: [g | u(4) | v(4) | hmean(4)]
#define YN (N1*PC)       // 637
#define DEGB ((EPn+255)/256)

// ================= k_mega: sim (b0) | lig-rs (b1) | pre (b2..65) | deg (b66..) =================

__global__ __launch_bounds__(256) void k_mega(
    // deg part
    const int* __restrict__ dst_p, int* __restrict__ deg,
    // sim part
    const int* __restrict__ lab_in, const int* __restrict__ bfs_i, const int* __restrict__ bfs_b,
    int* __restrict__ lab_idx, float* __restrict__ lab_means,
    int* __restrict__ dirs, int* __restrict__ dird, float* __restrict__ m_arr,
    float* __restrict__ e_arr, int* __restrict__ rec, int* __restrict__ Sout,
    // lig part (rs only — no Wl2 GEMV)
    const float* __restrict__ xg, const int* __restrict__ srcl, const int* __restrict__ dstl,
    const float* __restrict__ Wl1, const float* __restrict__ bl1, float* __restrict__ rs_g,
    // pre part
    const float* __restrict__ Wd2, const float* __restrict__ Wg, const float* __restrict__ Wh,
    const float* __restrict__ Wp2, const float* __restrict__ Wl2,
    float* __restrict__ Pm, float* __restrict__ Qp, float* __restrict__ Ql){
  const int bid = blockIdx.x;
  const int tid = threadIdx.x;

  if (bid >= 66){
    int e = (bid-66)*256 + tid;
    if (e < EPn) atomicAdd(&deg[dst_p[e]], 1);
    return;
  }

  if (bid == 0){
    // ---------- control sim: packed ctrl, no cross-lane latency chains ----------
    __shared__ int sv[Tn], sb[Tn];
    __shared__ int qarr[Tn+1];
    __shared__ int2 ctrl[Tn];        // x: u | doe<<8 | pop<<9 | act<<10 | timec<<16 ; y: v | bix<<8
    __shared__ float valuA[Tn], valvA[Tn];
    __shared__ float baseB[Tn][N1];
    __shared__ int slab[N1];
    __shared__ int cntL[NAn];
    if (tid < Tn){ sv[tid]=bfs_i[2*tid+1]; sb[tid]=bfs_b[tid]; }
    if (tid <= Tn) qarr[tid]=0;
    if (tid < NAn) cntL[tid]=0;
    if (tid < N1){ int l=(tid<NLl)? lab_in[tid] : (NAn-1); slab[tid]=l; lab_idx[tid]=l; }
    __syncthreads();
    if (tid < NLl) atomicAdd(&cntL[slab[tid]],1);
    if (tid == 0) qarr[0]=bfs_i[0];
    __syncthreads();
    if (tid < NAn){
      int c=cntL[tid];
      lab_means[tid]     = ((float)c + ((tid==NAn-1)?1.f:0.f))*(1.0f/49.0f);
      lab_means[NAn+tid] = (float)c*(1.0f/48.0f);
    }
    // ---- phase 0: scalar control recurrence ----
    if (tid == 0){
      dirs[192]=qarr[0]; dird[192]=bfs_i[1];
      int head=0, tail=1, ec=0, timec=0;
      for (int t=0;t<Tn;t++){
        int v = sv[t], bix = sb[t];
        int active = (tail>head)?1:0;
        int h = (head<=Tn)? head : Tn;
        int u = qarr[h];
        int is_stop = (v==NLl)?1:0;
        int pop = active & is_stop;
        int doe = active & (is_stop^1);
        ctrl[t] = make_int2(u | (doe<<8) | (pop<<9) | (active<<10) | (timec<<16), v | (bix<<8));
        if (doe){
          if (tail<=Tn) qarr[tail]=v;
          if (ec<192){ dirs[ec]=u; dird[ec]=v; dirs[ec+1]=v; dird[ec+1]=u; }
        }
        head+=pop; tail+=doe; ec+=2*doe; timec+=doe;
      }
      Sout[0]=ec/2;
    }
    __syncthreads();
    // ---- phase 0.5: rec outputs (parallel over t) ----
    if (tid < Tn){
      int2 c=ctrl[tid];
      rec[tid]=c.x&255; rec[Tn+tid]=c.y&255; rec[2*Tn+tid]=(c.y>>8)&3;
      rec[3*Tn+tid]=(c.x>>10)&1; rec[4*Tn+tid]=(c.x>>8)&1; rec[5*Tn+tid]=(c.x>>16)&255;
    }
    __syncthreads();
    // ---- phase A: per-lane val/closed/adj recurrence ----
    if (tid < 64){
      const int l = tid;
      int labv = (l<N1)? slab[l] : (NAn-1);
      float val;
      switch(labv){
        case 0: val=4.f; break; case 1: val=1.f; break; case 2: val=3.f; break;
        case 3: val=1.f; break; case 4: val=2.f; break; case 5: val=1.f; break;
        case 6: val=5.f; break; case 7: val=1.f; break; case 8: val=6.f; break;
        case 9: val=1.f; break; default: val=1000.f; break;
      }
      if (l>=N1) val=0.f;
      int closed=0;
      unsigned long long adjm=0ull;
      #pragma unroll 4
      for (int t=0;t<Tn;t++){
        int2 c=ctrl[t];
        int u=c.x&255, doe=(c.x>>8)&1, pop=(c.x>>9)&1;
        int v=c.y&255, bix=(c.y>>8)&3;
        float base = (val<1.f || closed || ((adjm>>u)&1ull)) ? NEGf : 0.f;
        if (l==u) base=NEGf;
        if (l<N1) baseB[t][l]=base;
        if (l==u) valuA[t]=val;
        if (l==v) valvA[t]=val;
        if (doe){
          float dec = (bix==0)?1.f:(bix==1)?2.f:(bix==2)?3.f:1.5f;
          if (l==u){ val-=dec; adjm |= (1ull<<v); }
          if (l==v){ val-=dec; adjm |= (1ull<<u); }
        }
        if (pop && l==u) closed=1;
      }
    }
    __syncthreads();
    // ---- phase B: finalize m/e outputs ----
    {
      const int lane=tid&63, wv=tid>>6;
      for (int t=wv; t<Tn; t+=4){
        float valu=valuA[t], valv=valvA[t];
        int v=sv[t], bix=sb[t];
        if (lane<N1){
          float mnou = (valu<1.f)? NEGf : baseB[t][lane];
          float m = mnou;
          if (lane==v) m=0.f;
          if (lane==NLl) m=0.f;
          m_arr[t*N1+lane]=m;
        }
        if (lane<4){
          float mnv = (valu<1.f)? NEGf : baseB[t][v];
          float mv = fminf(valu,valv);
          float e;
          if (mv<=0.f) e=NEGf;
          else if (mv<=1.f) e=((lane==1)||(lane==2))?NEGf:0.f;
          else if (mv<=2.f) e=(lane==2)?NEGf:0.f;
          else e=0.f;
          if (mnv <= NEGf*0.5f) e=NEGf;
          if (lane==bix) e=0.f;
          e_arr[t*4+lane]=e;
        }
      }
    }
    return;
  }

  if (bid == 1){
    // ---------- ligand GCN: compute rs only (all-LDS; Wl2 GEMV moved to Ql precompute) ----------
    __shared__ float sW[15*Dn];
    __shared__ __align__(16) float sagg[NLl][16];
    __shared__ float ow[NLl];
    __shared__ float sdinv[NLl];
    __shared__ int sdeg[NLl];
    __shared__ int ses[ELl], sed[ELl];
    __shared__ int slab2[NLl];
    if (tid<NLl){ sdeg[tid]=1; slab2[tid]=lab_in[tid]; }
    for (int i=tid;i<NLl*16;i+=256) sagg[i>>4][i&15]=0.f;
    for (int i=tid;i<15*Dn;i+=256) sW[i]=Wl1[i];
    __syncthreads();
    if (tid<ELl){ ses[tid]=srcl[tid]; sed[tid]=dstl[tid]; atomicAdd(&sdeg[dstl[tid]],1); }
    __syncthreads();
    if (tid<NLl) sdinv[tid]=rsqrtf((float)sdeg[tid]);
    __syncthreads();
    if (tid<NLl){
      float dv=sdinv[tid];
      ow[tid]=dv;
      for (int q=0;q<4;q++) sagg[tid][q]=xg[tid*4+q]*dv;
      sagg[tid][4+slab2[tid]]=dv;
    }
    __syncthreads();
    if (tid<ELl){
      int s=ses[tid], d=sed[tid];
      float dvs=sdinv[s];
      for (int q=0;q<4;q++) atomicAdd(&sagg[d][q], xg[s*4+q]*dvs);
      atomicAdd(&sagg[d][4+slab2[s]], dvs);
      atomicAdd(&ow[s], sdinv[d]);
    }
    __syncthreads();
    {
      int c=tid;
      float wcol[16];
      #pragma unroll
      for (int q=0;q<15;q++) wcol[q]=sW[q*Dn+c];
      wcol[15]=0.f;
      float b=bl1[c];
      float rsum=0.f;
      for (int d=0;d<NLl;d++){
        const float4* ar=(const float4*)sagg[d];
        float4 x0=ar[0],x1=ar[1],x2=ar[2],x3=ar[3];
        float a=0.f;
        a=fmaf(x0.x,wcol[0],a); a=fmaf(x0.y,wcol[1],a); a=fmaf(x0.z,wcol[2],a); a=fmaf(x0.w,wcol[3],a);
        a=fmaf(x1.x,wcol[4],a); a=fmaf(x1.y,wcol[5],a); a=fmaf(x1.z,wcol[6],a); a=fmaf(x1.w,wcol[7],a);
        a=fmaf(x2.x,wcol[8],a); a=fmaf(x2.y,wcol[9],a); a=fmaf(x2.z,wcol[10],a); a=fmaf(x2.w,wcol[11],a);
        a=fmaf(x3.x,wcol[12],a); a=fmaf(x3.y,wcol[13],a); a=fmaf(x3.z,wcol[14],a);
        float h=fmaxf(sdinv[d]*a + b, 0.f);
        rsum = fmaf(sdinv[d]*ow[d], h, rsum);
      }
      rs_g[c]=rsum*(1.0f/48.0f);
    }
    return;
  }

  {
    // ---------- pre: Pm row k + Qp row k + Ql row k, one k per wave ----------
    const int lane = tid&63, wv = tid>>6;
    const int k = (bid-2)*4 + wv;
    float pg=0.f;
    float4 pu=make_float4(0,0,0,0), pv=make_float4(0,0,0,0), ph=make_float4(0,0,0,0);
    float4 qp=make_float4(0,0,0,0), ql=make_float4(0,0,0,0);
    for (int q=0;q<4;q++){
      int n = lane + 64*q;
      float w = Wd2[(size_t)k*Dn+n];
      pg = fmaf(w, Wg[524+n], pg);
      float4 a=*(const float4*)&Wh[(size_t)(257+n)*4];
      float4 b=*(const float4*)&Wh[(size_t)(524+n)*4];
      float4 c=*(const float4*)&Wh[(size_t)(791+n)*4];
      pu.x=fmaf(w,a.x,pu.x); pu.y=fmaf(w,a.y,pu.y); pu.z=fmaf(w,a.z,pu.z); pu.w=fmaf(w,a.w,pu.w);
      pv.x=fmaf(w,b.x,pv.x); pv.y=fmaf(w,b.y,pv.y); pv.z=fmaf(w,b.z,pv.z); pv.w=fmaf(w,b.w,pv.w);
      ph.x=fmaf(w,c.x,ph.x); ph.y=fmaf(w,c.y,ph.y); ph.z=fmaf(w,c.z,ph.z); ph.w=fmaf(w,c.w,ph.w);
      float wp = Wp2[(size_t)k*Dn+n];
      float wl = Wl2[(size_t)k*Dn+n];
      float4 w1=*(const float4*)&Wh[(size_t)(1+n)*4];
      float4 w2=*(const float4*)&Wh[(size_t)(1058+n)*4];
      qp.x=fmaf(wp,w1.x,qp.x); qp.y=fmaf(wp,w1.y,qp.y); qp.z=fmaf(wp,w1.z,qp.z); qp.w=fmaf(wp,w1.w,qp.w);
      ql.x=fmaf(wl,w2.x,ql.x); ql.y=fmaf(wl,w2.y,ql.y); ql.z=fmaf(wl,w2.z,ql.z); ql.w=fmaf(wl,w2.w,ql.w);
    }
    for (int off=32; off>0; off>>=1){
      pg += __shfl_xor(pg,off);
      pu.x+=__shfl_xor(pu.x,off); pu.y+=__shfl_xor(pu.y,off); pu.z+=__shfl_xor(pu.z,off); pu.w+=__shfl_xor(pu.w,off);
      pv.x+=__shfl_xor(pv.x,off); pv.y+=__shfl_xor(pv.y,off); pv.z+=__shfl_xor(pv.z,off); pv.w+=__shfl_xor(pv.w,off);
      ph.x+=__shfl_xor(ph.x,off); ph.y+=__shfl_xor(ph.y,off); ph.z+=__shfl_xor(ph.z,off); ph.w+=__shfl_xor(ph.w,off);
      qp.x+=__shfl_xor(qp.x,off); qp.y+=__shfl_xor(qp.y,off); qp.z+=__shfl_xor(qp.z,off); qp.w+=__shfl_xor(qp.w,off);
      ql.x+=__shfl_xor(ql.x,off); ql.y+=__shfl_xor(ql.y,off); ql.z+=__shfl_xor(ql.z,off); ql.w+=__shfl_xor(ql.w,off);
    }
    if (lane==0){
      float* o = Pm + k*PC;
      o[0]=pg; o[1]=pu.x; o[2]=pu.y; o[3]=pu.z; o[4]=pu.w;
      o[5]=pv.x; o[6]=pv.y; o[7]=pv.z; o[8]=pv.w;
      o[9]=ph.x; o[10]=ph.y; o[11]=ph.z; o[12]=ph.w;
      *(float4*)&Qp[k*4] = qp;
      *(float4*)&Ql[k*4] = ql;
    }
    return;
  }
}

// ================= k_dx: dcp (b0..96) | xagg scatter (b97..) =================

__global__ __launch_bounds__(256) void k_dx(
    // xagg part
    const int* __restrict__ src_p, const int* __restrict__ dst_p, const float* __restrict__ xp,
    const int* __restrict__ deg, float* __restrict__ xagg, float* __restrict__ odegw,
    // dcp part
    const int* __restrict__ Sp, const int* __restrict__ dirs,
    const int* __restrict__ dird, const int* __restrict__ lab_idx,
    const float* __restrict__ Wd1, const float* __restrict__ bd1,
    const float* __restrict__ Pm, const int* __restrict__ rec,
    const float* __restrict__ m_arr, const float* __restrict__ e_arr,
    const float* __restrict__ Wg, const float* __restrict__ Wh,
    float* __restrict__ spart){
  const int bid = blockIdx.x;
  const int tid = threadIdx.x;

  if (bid >= NSTATES){
    // ---------- xagg scatter: 16 lanes per edge ----------
    int g = (bid-NSTATES)*256 + tid;
    int e = g>>4, c = g&15;
    if (e >= EPn) return;
    int s = src_p[e], d = dst_p[e];
    if (c < 15){
      float dvs = rsqrtf((float)(deg[s]+1));
      atomicAdd(&xagg[d*16+c], xp[s*15+c]*dvs);
    } else {
      float dvd = rsqrtf((float)(deg[d]+1));
      atomicAdd(&odegw[s], dvd);
    }
    return;
  }

  // ---------- dcp: decoder state k + per-step partials ----------
  int k = bid;
  if (k > Sp[0]) return;
  __shared__ float sW[11*Dn];
  __shared__ float sP[Dn*PC];
  __shared__ float hT[Dn*N1];
  __shared__ float cnt[N1*11];
  __shared__ float y1[YN];
  __shared__ float za[YN];
  __shared__ float sdinv[N1];
  __shared__ int sdeg[N1];
  __shared__ int se[192], sd[192];
  __shared__ int slab[N1];
  __shared__ int srec[6*Tn];
  int ecnt = (k==0)?1:(2*k);
  int base = (k==0)?192:0;
  if (tid<N1){ sdeg[tid]=1; slab[tid]=lab_idx[tid]; }
  for (int i=tid;i<N1*11;i+=256) cnt[i]=0.f;
  for (int i=tid;i<11*Dn;i+=256) sW[i]=Wd1[i];
  for (int i=tid;i<Dn*PC;i+=256) sP[i]=Pm[i];
  for (int i=tid;i<6*Tn;i+=256) srec[i]=rec[i];
  __syncthreads();
  if (tid<ecnt){ se[tid]=dirs[base+tid]; sd[tid]=dird[base+tid]; atomicAdd(&sdeg[sd[tid]],1); }
  __syncthreads();
  if (tid<N1) sdinv[tid]=rsqrtf((float)sdeg[tid]);
  __syncthreads();
  if (tid<N1) cnt[tid*11+slab[tid]] = sdinv[tid];
  __syncthreads();
  if (tid<ecnt) atomicAdd(&cnt[sd[tid]*11+slab[se[tid]]], sdinv[se[tid]]);
  __syncthreads();
  {
    int c=tid;
    float wreg[11];
    for (int a=0;a<11;a++) wreg[a]=sW[a*Dn+c];
    float b=bd1[c];
    for (int r=0;r<N1;r++){
      float s=0.f;
      for (int a=0;a<11;a++) s=fmaf(cnt[r*11+a], wreg[a], s);
      hT[c*N1+r]=fmaxf(sdinv[r]*s + b, 0.f);
    }
  }
  __syncthreads();
  for (int idx=tid; idx<YN; idx+=256){
    int r=idx/PC, j=idx-r*PC;
    float acc=0.f;
    for (int c=0;c<Dn;c++) acc=fmaf(hT[c*N1+r], sP[c*PC+j], acc);
    y1[idx]=acc;
    za[idx]=sdinv[r]*acc;
  }
  __syncthreads();
  for (int i=tid; i<ecnt*PC; i+=256){
    int e=i/PC, j=i-e*PC;
    atomicAdd(&za[sd[e]*PC+j], sdinv[se[e]]*y1[se[e]*PC+j]);
  }
  __syncthreads();
  for (int idx=tid; idx<YN; idx+=256){
    int r=idx/PC;
    za[idx]=sdinv[r]*za[idx];
  }
  __syncthreads();
  if (tid>=64) return;
  const int lane=tid;
  for (int t=0;t<Tn;t++){
    if (!srec[3*Tn+t] || srec[5*Tn+t]!=k) continue;
    const int u=srec[t], v=srec[Tn+t], doe=srec[4*Tn+t];
    float g = -INFINITY;
    float4 hm = make_float4(0,0,0,0);
    if (lane<N1){
      const float* zrow = za + lane*PC;
      g = zrow[0] + Wg[780+slab[lane]] + m_arr[t*N1+lane];
      hm.x=zrow[9]; hm.y=zrow[10]; hm.z=zrow[11]; hm.w=zrow[12];
    }
    float gv = __shfl(g, v);
    float gM = g;
    for (int off=32; off>0; off>>=1) gM = fmaxf(gM, __shfl_xor(gM, off));
    float ex = (lane<N1)? expf(g-gM) : 0.f;
    float gS = ex;
    for (int off=32; off>0; off>>=1){
      gS += __shfl_xor(gS, off);
      hm.x+=__shfl_xor(hm.x,off); hm.y+=__shfl_xor(hm.y,off);
      hm.z+=__shfl_xor(hm.z,off); hm.w+=__shfl_xor(hm.w,off);
    }
    if (lane==0){
      spart[t*5] = gv - gM - logf(gS);
      if (doe){
        const int lu=slab[u], lv=slab[v];
        const float tf=(float)k;
        for (int j=0;j<4;j++){
          float hmj = (j==0)?hm.x:(j==1)?hm.y:(j==2)?hm.z:hm.w;
          spart[t*5+1+j] = tf*Wh[j] + Wh[(513+lu)*4+j] + Wh[(780+lv)*4+j]
               + za[u*PC+1+j] + za[v*PC+5+j] + hmj*(1.0f/49.0f) + e_arr[4*t+j];
        }
      }
    }
  }
}

// ================= k_fuse: staged matvec + weighted rowsum =================

__global__ __launch_bounds__(256) void k_fuse(const float* __restrict__ xp, const float* __restrict__ xagg,
    const int* __restrict__ deg, const float* __restrict__ odegw,
    const float* __restrict__ Wp1, const float* __restrict__ bp1, float* __restrict__ zr){
  __shared__ float sx[CHN][16];
  __shared__ float sc[CHN];
  int tid = threadIdx.x;
  int base = blockIdx.x*CHN;
  float wcol[15];
  for (int k=0;k<15;k++) wcol[k]=Wp1[k*Dn+tid];
  float b = bp1[tid];
  for (int i=tid;i<CHN*16;i+=256){
    int n = base+(i>>4), c = i&15;
    float v = 0.f;
    if (n<NPn && c<15){
      float dv = rsqrtf((float)(deg[n]+1));
      v = (xagg[n*16+c] + xp[n*15+c]*dv)*dv;
    }
    sx[i>>4][i&15]=v;
  }
  for (int i=tid;i<CHN;i+=256){
    int n = base+i;
    float dv = (n<NPn)? rsqrtf((float)(deg[n]+1)) : 0.f;
    sc[i] = (n<NPn)? dv*(odegw[n]+dv) : 0.f;
  }
  __syncthreads();
  float acc = 0.f;
  int lim = (NPn-base < CHN)? (NPn-base) : CHN;
  for (int i=0;i<lim;i++){
    float d0 = b;
    for (int k=0;k<15;k++) d0 = fmaf(sx[i][k], wcol[k], d0);
    acc = fmaf(sc[i], fmaxf(d0,0.f), acc);
  }
  atomicAdd(&zr[tid], acc);
}

// ================= k_final: hconst via Qp/Ql dots + finish logp =================

__global__ __launch_bounds__(256) void k_final(const float* __restrict__ zr, const float* __restrict__ rs_g,
    const float* __restrict__ Qp, const float* __restrict__ Ql,
    const float* __restrict__ bp2, const float* __restrict__ bl2, const float* __restrict__ b2,
    const float* __restrict__ lm, const float* __restrict__ Wh, const float* __restrict__ bh,
    const int* __restrict__ rec, const float* __restrict__ spart, float* __restrict__ out){
  __shared__ float sr[Dn];
  __shared__ float rsg[Dn];
  __shared__ float hc4s[4];
  __shared__ float red[Tn];
  int tid=threadIdx.x;
  sr[tid]=zr[tid]*(1.0f/30000.0f);
  rsg[tid]=rs_g[tid];
  __syncthreads();
  if (tid<64){
    int lane=tid;
    float4 h=make_float4(0,0,0,0);
    for (int q=0;q<4;q++){
      int n=lane+64*q;
      float srn=sr[n], rsn=rsg[n], bpn=bp2[n], bln=bl2[n], bdn=b2[n];
      float4 qp=*(const float4*)&Qp[n*4];
      float4 ql=*(const float4*)&Ql[n*4];
      float4 w1=*(const float4*)&Wh[(size_t)(1+n)*4];
      float4 w2=*(const float4*)&Wh[(size_t)(1058+n)*4];
      float4 wu=*(const float4*)&Wh[(size_t)(257+n)*4];
      float4 wv=*(const float4*)&Wh[(size_t)(524+n)*4];
      float4 wh=*(const float4*)&Wh[(size_t)(791+n)*4];
      h.x += srn*qp.x + rsn*ql.x + bpn*w1.x + bln*w2.x + bdn*(wu.x+wv.x+wh.x);
      h.y += srn*qp.y + rsn*ql.y + bpn*w1.y + bln*w2.y + bdn*(wu.y+wv.y+wh.y);
      h.z += srn*qp.z + rsn*ql.z + bpn*w1.z + bln*w2.z + bdn*(wu.z+wv.z+wh.z);
      h.w += srn*qp.w + rsn*ql.w + bpn*w1.w + bln*w2.w + bdn*(wu.w+wv.w+wh.w);
    }
    if (lane<NAn){
      float4 wa=*(const float4*)&Wh[(size_t)(1047+lane)*4];
      float4 wb=*(const float4*)&Wh[(size_t)(1314+lane)*4];
      float aa=lm[lane], bb=lm[NAn+lane];
      h.x += aa*wa.x + bb*wb.x; h.y += aa*wa.y + bb*wb.y;
      h.z += aa*wa.z + bb*wb.z; h.w += aa*wa.w + bb*wb.w;
    }
    for (int off=32; off>0; off>>=1){
      h.x+=__shfl_xor(h.x,off); h.y+=__shfl_xor(h.y,off);
      h.z+=__shfl_xor(h.z,off); h.w+=__shfl_xor(h.w,off);
    }
    if (lane==0){
      hc4s[0]=h.x+bh[0]; hc4s[1]=h.y+bh[1]; hc4s[2]=h.z+bh[2]; hc4s[3]=h.w+bh[3];
    }
  }
  __syncthreads();
  if (tid<Tn){
    int t=tid;
    float res=0.f;
    if (rec[3*Tn+t]){
      res = spart[t*5];
      if (rec[4*Tn+t]){
        int bidx = rec[2*Tn+t];
        float h0=spart[t*5+1]+hc4s[0];
        float h1=spart[t*5+2]+hc4s[1];
        float h2=spart[t*5+3]+hc4s[2];
        float h3=spart[t*5+4]+hc4s[3];
        float M=fmaxf(fmaxf(h0,h1),fmaxf(h2,h3));
        float se2=expf(h0-M)+expf(h1-M)+expf(h2-M)+expf(h3-M);
        float hb=(bidx==0)?h0:(bidx==1)?h1:(bidx==2)?h2:h3;
        res += hb - M - logf(se2);
      }
    }
    red[t]=res;
  }
  __syncthreads();
  if (tid==0){
    float s=0.f;
    for (int t=0;t<Tn;t++) s+=red[t];
    out[0]=s;
  }
}

// ================= launch =================

extern "C" void kernel_launch(void* const* d_in, const int* in_sizes, int n_in,
                              void* d_out, int out_size, void* d_ws, size_t ws_size,
                              hipStream_t stream){
  const float* x_p      =(const float*)d_in[0];
  const int*   src_p    =(const int*)d_in[1];
  const int*   dst_p    =(const int*)d_in[2];
  const float* x_l_geom =(const float*)d_in[3];
  const int*   x_l_label=(const int*)d_in[4];
  const int*   src_l    =(const int*)d_in[5];
  const int*   dst_l    =(const int*)d_in[6];
  const int*   bfs_index=(const int*)d_in[7];
  const int*   bfs_bond =(const int*)d_in[8];
  const float* Wp1=(const float*)d_in[9];
  const float* bp1=(const float*)d_in[10];
  const float* Wp2=(const float*)d_in[11];
  const float* bp2=(const float*)d_in[12];
  const float* Wl1=(const float*)d_in[13];
  const float* bl1=(const float*)d_in[14];
  const float* Wl2=(const float*)d_in[15];
  const float* bl2=(const float*)d_in[16];
  const float* Wd1=(const float*)d_in[17];
  const float* bd1=(const float*)d_in[18];
  const float* Wd2=(const float*)d_in[19];
  const float* bd2=(const float*)d_in[20];
  const float* Wg =(const float*)d_in[23];
  const float* Wh =(const float*)d_in[25];
  const float* bh =(const float*)d_in[26];

  char* w=(char*)d_ws;
  size_t off=0;
  auto alloc=[&](size_t bytes)->char*{ char* p=w+off; off=(off+bytes+255)&~((size_t)255); return p; };
  // ---- contiguous zero-init region ----
  int*   deg    =(int*)alloc((size_t)NPn*4);
  float* odegw  =(float*)alloc((size_t)NPn*4);
  float* xagg   =(float*)alloc((size_t)NPn*16*4);
  float* zr     =(float*)alloc(Dn*4);
  size_t zero_span = off;
  // ---- rest (fully written before read) ----
  float* rs_g   =(float*)alloc(Dn*4);
  float* Pm     =(float*)alloc(Dn*PC*4);
  float* Qp     =(float*)alloc(Dn*4*4);
  float* Ql     =(float*)alloc(Dn*4*4);
  float* m_arr  =(float*)alloc((size_t)Tn*N1*4);
  float* e_arr  =(float*)alloc((size_t)Tn*4*4);
  int*   rec    =(int*)alloc((size_t)6*Tn*4);
  int*   dirs   =(int*)alloc(194*4);
  int*   dird   =(int*)alloc(194*4);
  int*   lab_idx=(int*)alloc(N1*4);
  float* lab_means=(float*)alloc(2*NAn*4);
  int*   Sval   =(int*)alloc(4);
  float* spart  =(float*)alloc((size_t)Tn*5*4);
  (void)in_sizes;(void)n_in;(void)ws_size;(void)out_size;

  hipMemsetAsync(d_ws, 0, zero_span, stream);

  // mega: sim (b0) | lig-rs (b1) | pre (b2..65) | deg (b66..)
  k_mega<<<66 + DEGB, 256, 0, stream>>>(
      dst_p, deg,
      x_l_label, bfs_index, bfs_bond, lab_idx, lab_means, dirs, dird, m_arr, e_arr, rec, Sval,
      x_l_geom, src_l, dst_l, Wl1, bl1, rs_g,
      Wd2, Wg, Wh, Wp2, Wl2, Pm, Qp, Ql);
  // dx: dcp (b0..96, hidden under the atomic storm) | xagg (b97..)
  k_dx<<<NSTATES + EPn*16/256, 256, 0, stream>>>(
      src_p, dst_p, x_p, deg, xagg, odegw,
      Sval, dirs, dird, lab_idx, Wd1, bd1, Pm, rec, m_arr, e_arr, Wg, Wh, spart);
  // fuse: pocket matvec + weighted rowsum
  k_fuse<<<(NPn+CHN-1)/CHN,256,0,stream>>>(x_p,xagg,deg,odegw,Wp1,bp1,zr);
  // final: hconst via Qp/Ql dots + finish 96 softmaxes + sum
  k_final<<<1,256,0,stream>>>(zr,rs_g,Qp,Ql,bp2,bl2,bd2,lab_means,Wh,bh,rec,spart,(float*)d_out);
}

// Round 11
// 243.571 us; speedup vs baseline: 1.5384x; 1.5384x over previous
//
#include <hip/hip_runtime.h>
#include <math.h>

#define NPn 30000
#define EPn 480000
#define NLl 48
#define ELl 144
#define Tn 96
#define NAn 11
#define Dn 256
#define N1 49
#define NEGf (-1000000000.0f)
#define NSTATES 97
#define CHN 125
#define PC 13            // P columns: [g | u(4) | v(4) | hmean(4)]
#define YN (N1*PC)       // 637
#define DEGB ((EPn+255)/256)

// ================= k_mega: sim (b0) | lig-rs (b1) | pre (b2..65) | deg (b66..) =================

__global__ __launch_bounds__(256) void k_mega(
    const int* __restrict__ dst_p, int* __restrict__ deg,
    const int* __restrict__ lab_in, const int* __restrict__ bfs_i, const int* __restrict__ bfs_b,
    int* __restrict__ lab_idx, float* __restrict__ lab_means,
    int* __restrict__ dirs, int* __restrict__ dird, float* __restrict__ m_arr,
    float* __restrict__ e_arr, int* __restrict__ rec, int* __restrict__ Sout,
    const float* __restrict__ xg, const int* __restrict__ srcl, const int* __restrict__ dstl,
    const float* __restrict__ Wl1, const float* __restrict__ bl1, float* __restrict__ rs_g,
    const float* __restrict__ Wd2, const float* __restrict__ Wg, const float* __restrict__ Wh,
    const float* __restrict__ Wp2, const float* __restrict__ Wl2,
    float* __restrict__ Pm, float* __restrict__ Qp, float* __restrict__ Ql){
  const int bid = blockIdx.x;
  const int tid = threadIdx.x;

  if (bid >= 66){
    int e = (bid-66)*256 + tid;
    if (e < EPn) atomicAdd(&deg[dst_p[e]], 1);
    return;
  }

  if (bid == 0){
    // ---------- control sim: packed ctrl, no cross-lane latency chains ----------
    __shared__ int sv[Tn], sb[Tn];
    __shared__ int qarr[Tn+1];
    __shared__ int2 ctrl[Tn];        // x: u | doe<<8 | pop<<9 | act<<10 | timec<<16 ; y: v | bix<<8
    __shared__ float valuA[Tn], valvA[Tn];
    __shared__ float baseB[Tn][N1];
    __shared__ int slab[N1];
    __shared__ int cntL[NAn];
    if (tid < Tn){ sv[tid]=bfs_i[2*tid+1]; sb[tid]=bfs_b[tid]; }
    if (tid <= Tn) qarr[tid]=0;
    if (tid < NAn) cntL[tid]=0;
    if (tid < N1){ int l=(tid<NLl)? lab_in[tid] : (NAn-1); slab[tid]=l; lab_idx[tid]=l; }
    __syncthreads();
    if (tid < NLl) atomicAdd(&cntL[slab[tid]],1);
    if (tid == 0) qarr[0]=bfs_i[0];
    __syncthreads();
    if (tid < NAn){
      int c=cntL[tid];
      lab_means[tid]     = ((float)c + ((tid==NAn-1)?1.f:0.f))*(1.0f/49.0f);
      lab_means[NAn+tid] = (float)c*(1.0f/48.0f);
    }
    if (tid == 0){
      dirs[192]=qarr[0]; dird[192]=bfs_i[1];
      int head=0, tail=1, ec=0, timec=0;
      for (int t=0;t<Tn;t++){
        int v = sv[t], bix = sb[t];
        int active = (tail>head)?1:0;
        int h = (head<=Tn)? head : Tn;
        int u = qarr[h];
        int is_stop = (v==NLl)?1:0;
        int pop = active & is_stop;
        int doe = active & (is_stop^1);
        ctrl[t] = make_int2(u | (doe<<8) | (pop<<9) | (active<<10) | (timec<<16), v | (bix<<8));
        if (doe){
          if (tail<=Tn) qarr[tail]=v;
          if (ec<192){ dirs[ec]=u; dird[ec]=v; dirs[ec+1]=v; dird[ec+1]=u; }
        }
        head+=pop; tail+=doe; ec+=2*doe; timec+=doe;
      }
      Sout[0]=ec/2;
    }
    __syncthreads();
    if (tid < Tn){
      int2 c=ctrl[tid];
      rec[tid]=c.x&255; rec[Tn+tid]=c.y&255; rec[2*Tn+tid]=(c.y>>8)&3;
      rec[3*Tn+tid]=(c.x>>10)&1; rec[4*Tn+tid]=(c.x>>8)&1; rec[5*Tn+tid]=(c.x>>16)&255;
    }
    __syncthreads();
    if (tid < 64){
      const int l = tid;
      int labv = (l<N1)? slab[l] : (NAn-1);
      float val;
      switch(labv){
        case 0: val=4.f; break; case 1: val=1.f; break; case 2: val=3.f; break;
        case 3: val=1.f; break; case 4: val=2.f; break; case 5: val=1.f; break;
        case 6: val=5.f; break; case 7: val=1.f; break; case 8: val=6.f; break;
        case 9: val=1.f; break; default: val=1000.f; break;
      }
      if (l>=N1) val=0.f;
      int closed=0;
      unsigned long long adjm=0ull;
      #pragma unroll 4
      for (int t=0;t<Tn;t++){
        int2 c=ctrl[t];
        int u=c.x&255, doe=(c.x>>8)&1, pop=(c.x>>9)&1;
        int v=c.y&255, bix=(c.y>>8)&3;
        float base = (val<1.f || closed || ((adjm>>u)&1ull)) ? NEGf : 0.f;
        if (l==u) base=NEGf;
        if (l<N1) baseB[t][l]=base;
        if (l==u) valuA[t]=val;
        if (l==v) valvA[t]=val;
        if (doe){
          float dec = (bix==0)?1.f:(bix==1)?2.f:(bix==2)?3.f:1.5f;
          if (l==u){ val-=dec; adjm |= (1ull<<v); }
          if (l==v){ val-=dec; adjm |= (1ull<<u); }
        }
        if (pop && l==u) closed=1;
      }
    }
    __syncthreads();
    {
      const int lane=tid&63, wv=tid>>6;
      for (int t=wv; t<Tn; t+=4){
        float valu=valuA[t], valv=valvA[t];
        int v=sv[t], bix=sb[t];
        if (lane<N1){
          float mnou = (valu<1.f)? NEGf : baseB[t][lane];
          float m = mnou;
          if (lane==v) m=0.f;
          if (lane==NLl) m=0.f;
          m_arr[t*N1+lane]=m;
        }
        if (lane<4){
          float mnv = (valu<1.f)? NEGf : baseB[t][v];
          float mv = fminf(valu,valv);
          float e;
          if (mv<=0.f) e=NEGf;
          else if (mv<=1.f) e=((lane==1)||(lane==2))?NEGf:0.f;
          else if (mv<=2.f) e=(lane==2)?NEGf:0.f;
          else e=0.f;
          if (mnv <= NEGf*0.5f) e=NEGf;
          if (lane==bix) e=0.f;
          e_arr[t*4+lane]=e;
        }
      }
    }
    return;
  }

  if (bid == 1){
    // ---------- ligand GCN: rs only (Wl2 GEMV folded into Ql precompute) ----------
    __shared__ float sW[15*Dn];
    __shared__ __align__(16) float sagg[NLl][16];
    __shared__ float ow[NLl];
    __shared__ float sdinv[NLl];
    __shared__ int sdeg[NLl];
    __shared__ int ses[ELl], sed[ELl];
    __shared__ int slab2[NLl];
    if (tid<NLl){ sdeg[tid]=1; slab2[tid]=lab_in[tid]; }
    for (int i=tid;i<NLl*16;i+=256) sagg[i>>4][i&15]=0.f;
    for (int i=tid;i<15*Dn;i+=256) sW[i]=Wl1[i];
    __syncthreads();
    if (tid<ELl){ ses[tid]=srcl[tid]; sed[tid]=dstl[tid]; atomicAdd(&sdeg[dstl[tid]],1); }
    __syncthreads();
    if (tid<NLl) sdinv[tid]=rsqrtf((float)sdeg[tid]);
    __syncthreads();
    if (tid<NLl){
      float dv=sdinv[tid];
      ow[tid]=dv;
      for (int q=0;q<4;q++) sagg[tid][q]=xg[tid*4+q]*dv;
      sagg[tid][4+slab2[tid]]=dv;
    }
    __syncthreads();
    if (tid<ELl){
      int s=ses[tid], d=sed[tid];
      float dvs=sdinv[s];
      for (int q=0;q<4;q++) atomicAdd(&sagg[d][q], xg[s*4+q]*dvs);
      atomicAdd(&sagg[d][4+slab2[s]], dvs);
      atomicAdd(&ow[s], sdinv[d]);
    }
    __syncthreads();
    {
      int c=tid;
      float wcol[16];
      #pragma unroll
      for (int q=0;q<15;q++) wcol[q]=sW[q*Dn+c];
      wcol[15]=0.f;
      float b=bl1[c];
      float rsum=0.f;
      for (int d=0;d<NLl;d++){
        const float4* ar=(const float4*)sagg[d];
        float4 x0=ar[0],x1=ar[1],x2=ar[2],x3=ar[3];
        float a=0.f;
        a=fmaf(x0.x,wcol[0],a); a=fmaf(x0.y,wcol[1],a); a=fmaf(x0.z,wcol[2],a); a=fmaf(x0.w,wcol[3],a);
        a=fmaf(x1.x,wcol[4],a); a=fmaf(x1.y,wcol[5],a); a=fmaf(x1.z,wcol[6],a); a=fmaf(x1.w,wcol[7],a);
        a=fmaf(x2.x,wcol[8],a); a=fmaf(x2.y,wcol[9],a); a=fmaf(x2.z,wcol[10],a); a=fmaf(x2.w,wcol[11],a);
        a=fmaf(x3.x,wcol[12],a); a=fmaf(x3.y,wcol[13],a); a=fmaf(x3.z,wcol[14],a);
        float h=fmaxf(sdinv[d]*a + b, 0.f);
        rsum = fmaf(sdinv[d]*ow[d], h, rsum);
      }
      rs_g[c]=rsum*(1.0f/48.0f);
    }
    return;
  }

  {
    // ---------- pre: Pm row k + Qp row k + Ql row k, one k per wave ----------
    const int lane = tid&63, wv = tid>>6;
    const int k = (bid-2)*4 + wv;
    float pg=0.f;
    float4 pu=make_float4(0,0,0,0), pv=make_float4(0,0,0,0), ph=make_float4(0,0,0,0);
    float4 qp=make_float4(0,0,0,0), ql=make_float4(0,0,0,0);
    for (int q=0;q<4;q++){
      int n = lane + 64*q;
      float w = Wd2[(size_t)k*Dn+n];
      pg = fmaf(w, Wg[524+n], pg);
      float4 a=*(const float4*)&Wh[(size_t)(257+n)*4];
      float4 b=*(const float4*)&Wh[(size_t)(524+n)*4];
      float4 c=*(const float4*)&Wh[(size_t)(791+n)*4];
      pu.x=fmaf(w,a.x,pu.x); pu.y=fmaf(w,a.y,pu.y); pu.z=fmaf(w,a.z,pu.z); pu.w=fmaf(w,a.w,pu.w);
      pv.x=fmaf(w,b.x,pv.x); pv.y=fmaf(w,b.y,pv.y); pv.z=fmaf(w,b.z,pv.z); pv.w=fmaf(w,b.w,pv.w);
      ph.x=fmaf(w,c.x,ph.x); ph.y=fmaf(w,c.y,ph.y); ph.z=fmaf(w,c.z,ph.z); ph.w=fmaf(w,c.w,ph.w);
      float wp = Wp2[(size_t)k*Dn+n];
      float wl = Wl2[(size_t)k*Dn+n];
      float4 w1=*(const float4*)&Wh[(size_t)(1+n)*4];
      float4 w2=*(const float4*)&Wh[(size_t)(1058+n)*4];
      qp.x=fmaf(wp,w1.x,qp.x); qp.y=fmaf(wp,w1.y,qp.y); qp.z=fmaf(wp,w1.z,qp.z); qp.w=fmaf(wp,w1.w,qp.w);
      ql.x=fmaf(wl,w2.x,ql.x); ql.y=fmaf(wl,w2.y,ql.y); ql.z=fmaf(wl,w2.z,ql.z); ql.w=fmaf(wl,w2.w,ql.w);
    }
    for (int off=32; off>0; off>>=1){
      pg += __shfl_xor(pg,off);
      pu.x+=__shfl_xor(pu.x,off); pu.y+=__shfl_xor(pu.y,off); pu.z+=__shfl_xor(pu.z,off); pu.w+=__shfl_xor(pu.w,off);
      pv.x+=__shfl_xor(pv.x,off); pv.y+=__shfl_xor(pv.y,off); pv.z+=__shfl_xor(pv.z,off); pv.w+=__shfl_xor(pv.w,off);
      ph.x+=__shfl_xor(ph.x,off); ph.y+=__shfl_xor(ph.y,off); ph.z+=__shfl_xor(ph.z,off); ph.w+=__shfl_xor(ph.w,off);
      qp.x+=__shfl_xor(qp.x,off); qp.y+=__shfl_xor(qp.y,off); qp.z+=__shfl_xor(qp.z,off); qp.w+=__shfl_xor(qp.w,off);
      ql.x+=__shfl_xor(ql.x,off); ql.y+=__shfl_xor(ql.y,off); ql.z+=__shfl_xor(ql.z,off); ql.w+=__shfl_xor(ql.w,off);
    }
    if (lane==0){
      float* o = Pm + k*PC;
      o[0]=pg; o[1]=pu.x; o[2]=pu.y; o[3]=pu.z; o[4]=pu.w;
      o[5]=pv.x; o[6]=pv.y; o[7]=pv.z; o[8]=pv.w;
      o[9]=ph.x; o[10]=ph.y; o[11]=ph.z; o[12]=ph.w;
      *(float4*)&Qp[k*4] = qp;
      *(float4*)&Ql[k*4] = ql;
    }
    return;
  }
}

// ================= k_xagg: standalone zero-LDS scatter (full occupancy) =================

__global__ void k_xagg(const int* __restrict__ src, const int* __restrict__ dst,
                       const float* __restrict__ xp, const int* __restrict__ deg,
                       float* __restrict__ xagg, float* __restrict__ odegw){
  int g = blockIdx.x*blockDim.x + threadIdx.x;
  int e = g>>4, c = g&15;
  if (e >= EPn) return;
  int s = src[e], d = dst[e];
  if (c < 15){
    float dvs = rsqrtf((float)(deg[s]+1));
    atomicAdd(&xagg[d*16+c], xp[s*15+c]*dvs);
  } else {
    float dvd = rsqrtf((float)(deg[d]+1));
    atomicAdd(&odegw[s], dvd);
  }
}

// ================= k_df: dcp (b0..96) | fuse (b97..336) — LDS overlaid =================
// Both roles are grid-limited (337 blocks < 1.5/CU), so the large dcp LDS footprint
// does not throttle occupancy. LDS overlay: one char buffer, per-role casts.

#define DCP_SP    0
#define DCP_HT    13312
#define DCP_CNT   63488
#define DCP_Y1    65648
#define DCP_ZA    68208
#define DCP_SDINV 70768
#define DCP_SDEG  70976
#define DCP_SE    71184
#define DCP_SD    71952
#define DCP_SLAB  72720
#define DCP_SREC  72928
#define SMEM_SZ   75232

__global__ __launch_bounds__(256) void k_df(
    // fuse part
    const float* __restrict__ xp, const float* __restrict__ xagg,
    const int* __restrict__ deg, const float* __restrict__ odegw,
    const float* __restrict__ Wp1, const float* __restrict__ bp1, float* __restrict__ zr,
    // dcp part
    const int* __restrict__ Sp, const int* __restrict__ dirs,
    const int* __restrict__ dird, const int* __restrict__ lab_idx,
    const float* __restrict__ Wd1, const float* __restrict__ bd1,
    const float* __restrict__ Pm, const int* __restrict__ rec,
    const float* __restrict__ m_arr, const float* __restrict__ e_arr,
    const float* __restrict__ Wg, const float* __restrict__ Wh,
    float* __restrict__ spart){
  __shared__ __align__(16) char smem[SMEM_SZ];
  const int bid = blockIdx.x;
  const int tid = threadIdx.x;

  if (bid >= NSTATES){
    // ---------- fuse: staged matvec + weighted rowsum ----------
    float* sx = (float*)smem;            // [CHN][16]
    float* sc = (float*)(smem + CHN*16*4);
    int base = (bid-NSTATES)*CHN;
    float wcol[15];
    for (int k=0;k<15;k++) wcol[k]=Wp1[k*Dn+tid];
    float b = bp1[tid];
    for (int i=tid;i<CHN*16;i+=256){
      int n = base+(i>>4), c = i&15;
      float v = 0.f;
      if (n<NPn && c<15){
        float dv = rsqrtf((float)(deg[n]+1));
        v = (xagg[n*16+c] + xp[n*15+c]*dv)*dv;
      }
      sx[i]=v;
    }
    for (int i=tid;i<CHN;i+=256){
      int n = base+i;
      float dv = (n<NPn)? rsqrtf((float)(deg[n]+1)) : 0.f;
      sc[i] = (n<NPn)? dv*(odegw[n]+dv) : 0.f;
    }
    __syncthreads();
    float acc = 0.f;
    int lim = (NPn-base < CHN)? (NPn-base) : CHN;
    for (int i=0;i<lim;i++){
      float d0 = b;
      for (int k=0;k<15;k++) d0 = fmaf(sx[i*16+k], wcol[k], d0);
      acc = fmaf(sc[i], fmaxf(d0,0.f), acc);
    }
    atomicAdd(&zr[tid], acc);
    return;
  }

  // ---------- dcp: decoder state k + per-step partials ----------
  int k = bid;
  if (k > Sp[0]) return;
  float* sP    = (float*)(smem+DCP_SP);
  float* hT    = (float*)(smem+DCP_HT);
  float* cnt   = (float*)(smem+DCP_CNT);
  float* y1    = (float*)(smem+DCP_Y1);
  float* za    = (float*)(smem+DCP_ZA);
  float* sdinv = (float*)(smem+DCP_SDINV);
  int*   sdeg  = (int*)(smem+DCP_SDEG);
  int*   se    = (int*)(smem+DCP_SE);
  int*   sd    = (int*)(smem+DCP_SD);
  int*   slab  = (int*)(smem+DCP_SLAB);
  int*   srec  = (int*)(smem+DCP_SREC);
  int ecnt = (k==0)?1:(2*k);
  int base = (k==0)?192:0;
  if (tid<N1){ sdeg[tid]=1; slab[tid]=lab_idx[tid]; }
  for (int i=tid;i<N1*11;i+=256) cnt[i]=0.f;
  for (int i=tid;i<Dn*PC;i+=256) sP[i]=Pm[i];
  for (int i=tid;i<6*Tn;i+=256) srec[i]=rec[i];
  __syncthreads();
  if (tid<ecnt){ se[tid]=dirs[base+tid]; sd[tid]=dird[base+tid]; atomicAdd(&sdeg[sd[tid]],1); }
  __syncthreads();
  if (tid<N1) sdinv[tid]=rsqrtf((float)sdeg[tid]);
  __syncthreads();
  if (tid<N1) cnt[tid*11+slab[tid]] = sdinv[tid];
  __syncthreads();
  if (tid<ecnt) atomicAdd(&cnt[sd[tid]*11+slab[se[tid]]], sdinv[se[tid]]);
  __syncthreads();
  {
    int c=tid;
    float wreg[11];
    for (int a=0;a<11;a++) wreg[a]=Wd1[a*Dn+c];   // direct coalesced, no LDS staging
    float b=bd1[c];
    for (int r=0;r<N1;r++){
      float s=0.f;
      for (int a=0;a<11;a++) s=fmaf(cnt[r*11+a], wreg[a], s);
      hT[c*N1+r]=fmaxf(sdinv[r]*s + b, 0.f);
    }
  }
  __syncthreads();
  for (int idx=tid; idx<YN; idx+=256){
    int r=idx/PC, j=idx-r*PC;
    float acc=0.f;
    for (int c=0;c<Dn;c++) acc=fmaf(hT[c*N1+r], sP[c*PC+j], acc);
    y1[idx]=acc;
    za[idx]=sdinv[r]*acc;
  }
  __syncthreads();
  for (int i=tid; i<ecnt*PC; i+=256){
    int e=i/PC, j=i-e*PC;
    atomicAdd(&za[sd[e]*PC+j], sdinv[se[e]]*y1[se[e]*PC+j]);
  }
  __syncthreads();
  for (int idx=tid; idx<YN; idx+=256){
    int r=idx/PC;
    za[idx]=sdinv[r]*za[idx];
  }
  __syncthreads();
  if (tid>=64) return;
  const int lane=tid;
  for (int t=0;t<Tn;t++){
    if (!srec[3*Tn+t] || srec[5*Tn+t]!=k) continue;
    const int u=srec[t], v=srec[Tn+t], doe=srec[4*Tn+t];
    float g = -INFINITY;
    float4 hm = make_float4(0,0,0,0);
    if (lane<N1){
      const float* zrow = za + lane*PC;
      g = zrow[0] + Wg[780+slab[lane]] + m_arr[t*N1+lane];
      hm.x=zrow[9]; hm.y=zrow[10]; hm.z=zrow[11]; hm.w=zrow[12];
    }
    float gv = __shfl(g, v);
    float gM = g;
    for (int off=32; off>0; off>>=1) gM = fmaxf(gM, __shfl_xor(gM, off));
    float ex = (lane<N1)? expf(g-gM) : 0.f;
    float gS = ex;
    for (int off=32; off>0; off>>=1){
      gS += __shfl_xor(gS, off);
      hm.x+=__shfl_xor(hm.x,off); hm.y+=__shfl_xor(hm.y,off);
      hm.z+=__shfl_xor(hm.z,off); hm.w+=__shfl_xor(hm.w,off);
    }
    if (lane==0){
      spart[t*5] = gv - gM - logf(gS);
      if (doe){
        const int lu=slab[u], lv=slab[v];
        const float tf=(float)k;
        for (int j=0;j<4;j++){
          float hmj = (j==0)?hm.x:(j==1)?hm.y:(j==2)?hm.z:hm.w;
          spart[t*5+1+j] = tf*Wh[j] + Wh[(513+lu)*4+j] + Wh[(780+lv)*4+j]
               + za[u*PC+1+j] + za[v*PC+5+j] + hmj*(1.0f/49.0f) + e_arr[4*t+j];
        }
      }
    }
  }
}

// ================= k_final: hconst via Qp/Ql dots + finish logp =================

__global__ __launch_bounds__(256) void k_final(const float* __restrict__ zr, const float* __restrict__ rs_g,
    const float* __restrict__ Qp, const float* __restrict__ Ql,
    const float* __restrict__ bp2, const float* __restrict__ bl2, const float* __restrict__ b2,
    const float* __restrict__ lm, const float* __restrict__ Wh, const float* __restrict__ bh,
    const int* __restrict__ rec, const float* __restrict__ spart, float* __restrict__ out){
  __shared__ float sr[Dn];
  __shared__ float rsg[Dn];
  __shared__ float hc4s[4];
  __shared__ float red[Tn];
  int tid=threadIdx.x;
  sr[tid]=zr[tid]*(1.0f/30000.0f);
  rsg[tid]=rs_g[tid];
  __syncthreads();
  if (tid<64){
    int lane=tid;
    float4 h=make_float4(0,0,0,0);
    for (int q=0;q<4;q++){
      int n=lane+64*q;
      float srn=sr[n], rsn=rsg[n], bpn=bp2[n], bln=bl2[n], bdn=b2[n];
      float4 qp=*(const float4*)&Qp[n*4];
      float4 ql=*(const float4*)&Ql[n*4];
      float4 w1=*(const float4*)&Wh[(size_t)(1+n)*4];
      float4 w2=*(const float4*)&Wh[(size_t)(1058+n)*4];
      float4 wu=*(const float4*)&Wh[(size_t)(257+n)*4];
      float4 wv=*(const float4*)&Wh[(size_t)(524+n)*4];
      float4 wh=*(const float4*)&Wh[(size_t)(791+n)*4];
      h.x += srn*qp.x + rsn*ql.x + bpn*w1.x + bln*w2.x + bdn*(wu.x+wv.x+wh.x);
      h.y += srn*qp.y + rsn*ql.y + bpn*w1.y + bln*w2.y + bdn*(wu.y+wv.y+wh.y);
      h.z += srn*qp.z + rsn*ql.z + bpn*w1.z + bln*w2.z + bdn*(wu.z+wv.z+wh.z);
      h.w += srn*qp.w + rsn*ql.w + bpn*w1.w + bln*w2.w + bdn*(wu.w+wv.w+wh.w);
    }
    if (lane<NAn){
      float4 wa=*(const float4*)&Wh[(size_t)(1047+lane)*4];
      float4 wb=*(const float4*)&Wh[(size_t)(1314+lane)*4];
      float aa=lm[lane], bb=lm[NAn+lane];
      h.x += aa*wa.x + bb*wb.x; h.y += aa*wa.y + bb*wb.y;
      h.z += aa*wa.z + bb*wb.z; h.w += aa*wa.w + bb*wb.w;
    }
    for (int off=32; off>0; off>>=1){
      h.x+=__shfl_xor(h.x,off); h.y+=__shfl_xor(h.y,off);
      h.z+=__shfl_xor(h.z,off); h.w+=__shfl_xor(h.w,off);
    }
    if (lane==0){
      hc4s[0]=h.x+bh[0]; hc4s[1]=h.y+bh[1]; hc4s[2]=h.z+bh[2]; hc4s[3]=h.w+bh[3];
    }
  }
  __syncthreads();
  if (tid<Tn){
    int t=tid;
    float res=0.f;
    if (rec[3*Tn+t]){
      res = spart[t*5];
      if (rec[4*Tn+t]){
        int bidx = rec[2*Tn+t];
        float h0=spart[t*5+1]+hc4s[0];
        float h1=spart[t*5+2]+hc4s[1];
        float h2=spart[t*5+3]+hc4s[2];
        float h3=spart[t*5+4]+hc4s[3];
        float M=fmaxf(fmaxf(h0,h1),fmaxf(h2,h3));
        float se2=expf(h0-M)+expf(h1-M)+expf(h2-M)+expf(h3-M);
        float hb=(bidx==0)?h0:(bidx==1)?h1:(bidx==2)?h2:h3;
        res += hb - M - logf(se2);
      }
    }
    red[t]=res;
  }
  __syncthreads();
  if (tid==0){
    float s=0.f;
    for (int t=0;t<Tn;t++) s+=red[t];
    out[0]=s;
  }
}

// ================= launch =================

extern "C" void kernel_launch(void* const* d_in, const int* in_sizes, int n_in,
                              void* d_out, int out_size, void* d_ws, size_t ws_size,
                              hipStream_t stream){
  const float* x_p      =(const float*)d_in[0];
  const int*   src_p    =(const int*)d_in[1];
  const int*   dst_p    =(const int*)d_in[2];
  const float* x_l_geom =(const float*)d_in[3];
  const int*   x_l_label=(const int*)d_in[4];
  const int*   src_l    =(const int*)d_in[5];
  const int*   dst_l    =(const int*)d_in[6];
  const int*   bfs_index=(const int*)d_in[7];
  const int*   bfs_bond =(const int*)d_in[8];
  const float* Wp1=(const float*)d_in[9];
  const float* bp1=(const float*)d_in[10];
  const float* Wp2=(const float*)d_in[11];
  const float* bp2=(const float*)d_in[12];
  const float* Wl1=(const float*)d_in[13];
  const float* bl1=(const float*)d_in[14];
  const float* Wl2=(const float*)d_in[15];
  const float* bl2=(const float*)d_in[16];
  const float* Wd1=(const float*)d_in[17];
  const float* bd1=(const float*)d_in[18];
  const float* Wd2=(const float*)d_in[19];
  const float* bd2=(const float*)d_in[20];
  const float* Wg =(const float*)d_in[23];
  const float* Wh =(const float*)d_in[25];
  const float* bh =(const float*)d_in[26];

  char* w=(char*)d_ws;
  size_t off=0;
  auto alloc=[&](size_t bytes)->char*{ char* p=w+off; off=(off+bytes+255)&~((size_t)255); return p; };
  // ---- contiguous zero-init region ----
  int*   deg    =(int*)alloc((size_t)NPn*4);
  float* odegw  =(float*)alloc((size_t)NPn*4);
  float* xagg   =(float*)alloc((size_t)NPn*16*4);
  float* zr     =(float*)alloc(Dn*4);
  size_t zero_span = off;
  // ---- rest (fully written before read) ----
  float* rs_g   =(float*)alloc(Dn*4);
  float* Pm     =(float*)alloc(Dn*PC*4);
  float* Qp     =(float*)alloc(Dn*4*4);
  float* Ql     =(float*)alloc(Dn*4*4);
  float* m_arr  =(float*)alloc((size_t)Tn*N1*4);
  float* e_arr  =(float*)alloc((size_t)Tn*4*4);
  int*   rec    =(int*)alloc((size_t)6*Tn*4);
  int*   dirs   =(int*)alloc(194*4);
  int*   dird   =(int*)alloc(194*4);
  int*   lab_idx=(int*)alloc(N1*4);
  float* lab_means=(float*)alloc(2*NAn*4);
  int*   Sval   =(int*)alloc(4);
  float* spart  =(float*)alloc((size_t)Tn*5*4);
  (void)in_sizes;(void)n_in;(void)ws_size;(void)out_size;

  hipMemsetAsync(d_ws, 0, zero_span, stream);

  // mega: sim (b0) | lig-rs (b1) | pre (b2..65) | deg (b66..)
  k_mega<<<66 + DEGB, 256, 0, stream>>>(
      dst_p, deg,
      x_l_label, bfs_index, bfs_bond, lab_idx, lab_means, dirs, dird, m_arr, e_arr, rec, Sval,
      x_l_geom, src_l, dst_l, Wl1, bl1, rs_g,
      Wd2, Wg, Wh, Wp2, Wl2, Pm, Qp, Ql);
  // xagg: standalone zero-LDS scatter at full occupancy
  k_xagg<<<EPn*16/256, 256, 0, stream>>>(src_p, dst_p, x_p, deg, xagg, odegw);
  // df: dcp (b0..96) | fuse (b97..336) — grid-limited, LDS overlay
  k_df<<<NSTATES + (NPn+CHN-1)/CHN, 256, 0, stream>>>(
      x_p, xagg, deg, odegw, Wp1, bp1, zr,
      Sval, dirs, dird, lab_idx, Wd1, bd1, Pm, rec, m_arr, e_arr, Wg, Wh, spart);
  // final: hconst via Qp/Ql dots + finish 96 softmaxes + sum
  k_final<<<1,256,0,stream>>>(zr,rs_g,Qp,Ql,bp2,bl2,bd2,lab_means,Wh,bh,rec,spart,(float*)d_out);
}